// Round 5
// baseline (314.163 us; speedup 1.0000x reference)
//
#include <hip/hip_runtime.h>

#define NPTS 65536
#define KC   1024
#define DD   512

using bf16x8 = __attribute__((ext_vector_type(8))) __bf16;
using f32x4  = __attribute__((ext_vector_type(4))) float;

// ---- async global->LDS, 16B per lane. LDS dest = wave-uniform base + lane*16.
__device__ __forceinline__ void gld_lds16(const void* g, void* lds_base) {
  __builtin_amdgcn_global_load_lds(
      (const __attribute__((address_space(1))) unsigned int*)(uintptr_t)g,
      (__attribute__((address_space(3))) unsigned int*)(unsigned int)(uintptr_t)lds_base,
      16, 0, 0);
}

// pack float4 -> 4 bf16 (truncation)
__device__ __forceinline__ uint2 pack4(const float4& v) {
  uint2 r;
  r.x = (__float_as_uint(v.x) >> 16) | (__float_as_uint(v.y) & 0xffff0000u);
  r.y = (__float_as_uint(v.z) >> 16) | (__float_as_uint(v.w) & 0xffff0000u);
  return r;
}

// ================= FAST PATH =================

// fused prep: blocks [0,256) convert centers->cb + c2 (1024 rows);
// blocks [256, 256+2048) convert x->xb (8 rows/wave) + x2 block partials.
// Pure streaming: no gathers, no long dependence chains.
__global__ __launch_bounds__(256) void prep_kernel(
    const float* __restrict__ x, const float* __restrict__ centers,
    uint4* __restrict__ xb, uint4* __restrict__ cb,
    float* __restrict__ c2, float* __restrict__ px2) {
  const int w = threadIdx.x >> 6, l = threadIdx.x & 63;
  if (blockIdx.x < 256) {
    const int row = blockIdx.x * 4 + w;
    const float4* cf4 = (const float4*)centers;
    float4 a = cf4[row * 128 + 2 * l];
    float4 b = cf4[row * 128 + 2 * l + 1];
    uint2 pa = pack4(a), pb = pack4(b);
    cb[row * 64 + l] = make_uint4(pa.x, pa.y, pb.x, pb.y);
    float s = a.x * a.x + a.y * a.y + a.z * a.z + a.w * a.w +
              b.x * b.x + b.y * b.y + b.z * b.z + b.w * b.w;
#pragma unroll
    for (int off = 32; off; off >>= 1) s += __shfl_down(s, off, 64);
    if (l == 0) c2[row] = s;
    return;
  }
  const int xblk = blockIdx.x - 256;         // 0..2047
  const int base = xblk * 32 + w * 8;        // 8 rows per wave
  const float4* xf4 = (const float4*)x;
  float s = 0.f;
#pragma unroll
  for (int p = 0; p < 8; p++) {
    const int row = base + p;
    float4 a = xf4[row * 128 + 2 * l];
    float4 b = xf4[row * 128 + 2 * l + 1];
    uint2 pa = pack4(a), pb = pack4(b);
    xb[row * 64 + l] = make_uint4(pa.x, pa.y, pb.x, pb.y);
    s += a.x * a.x + a.y * a.y + a.z * a.z + a.w * a.w +
         b.x * b.x + b.y * b.y + b.z * b.z + b.w * b.w;
  }
#pragma unroll
  for (int off = 32; off; off >>= 1) s += __shfl_down(s, off, 64);
  __shared__ float ps[4];
  if (l == 0) ps[w] = s;
  __syncthreads();
  if (threadIdx.x == 0) px2[xblk] = ps[0] + ps[1] + ps[2] + ps[3];
}

// bf16 MFMA argmin + loss capture.  BM=128 x BN=256, BK=64.
// loss term: for row m, col n == y[m]:  (c2[n] - 2 dot) captured during fold.
__global__ __launch_bounds__(256, 3) void gemm_argmin(
    const uint4* __restrict__ xb, const uint4* __restrict__ cb,
    const float* __restrict__ c2, const int* __restrict__ y,
    float* __restrict__ ynew_out, float* __restrict__ ploss) {
  __shared__ uint4 As[1024];   // 128 rows x 8 slots (64 bf16/row chunk)
  __shared__ uint4 Bs[2048];   // 256 rows x 8 slots
  __shared__ float c2s[1024];
  __shared__ int   ys[128];
  __shared__ float lred[4];

  const int t = threadIdx.x;
  const int w = t >> 6, l = t & 63;
  const int wm = w >> 1, wn = w & 1;   // wave: 64 rows x 128 cols
  const int q4 = l >> 4, m16 = l & 15;
  const int row0 = blockIdx.x * 128;

#pragma unroll
  for (int i = 0; i < 4; i++) c2s[t + 256 * i] = c2[t + 256 * i];
  if (t < 128) ys[t] = y[row0 + t];
  __syncthreads();

  // per-lane copy of y for the 16 accumulator rows this lane owns
  int ysv[16];
#pragma unroll
  for (int i = 0; i < 4; i++)
#pragma unroll
    for (int r = 0; r < 4; r++)
      ysv[i * 4 + r] = ys[wm * 64 + i * 16 + q4 * 4 + r];

  // staging lane mapping: chunk covers 8 rows; lane l -> row l>>3, slot l&7,
  // source oct (l&7)^(l>>3)  => LDS slot(r,oct) = oct ^ (r&7)  (conflict-free)
  const int r_l = l >> 3;
  const int o_l = (l & 7) ^ r_l;
  int aidx[4];
#pragma unroll
  for (int q = 0; q < 4; q++)
    aidx[q] = (row0 + (w * 4 + q) * 8 + r_l) * 64 + o_l;
  int bsrc[8];
#pragma unroll
  for (int q = 0; q < 8; q++)
    bsrc[q] = ((w * 8 + q) * 8 + r_l) * 64 + o_l;

  const int xr = m16 & 7;

  float best[16];
  int bi_[16];
#pragma unroll
  for (int i = 0; i < 16; i++) { best[i] = 3.4e38f; bi_[i] = 0; }
  float lsum = 0.f;

  for (int n0 = 0; n0 < KC; n0 += 256) {
    f32x4 acc[4][8];
#pragma unroll
    for (int i = 0; i < 4; i++)
#pragma unroll
      for (int j = 0; j < 8; j++) acc[i][j] = (f32x4){0.f, 0.f, 0.f, 0.f};

    const uint4* bbase = cb + n0 * 64;

    for (int ks = 0; ks < 8; ks++) {
      __syncthreads();  // previous iteration's fragment reads complete
#pragma unroll
      for (int q = 0; q < 4; q++)
        gld_lds16(xb + aidx[q] + ks * 8, &As[(w * 4 + q) * 64]);
#pragma unroll
      for (int q = 0; q < 8; q++)
        gld_lds16(bbase + bsrc[q] + ks * 8, &Bs[(w * 8 + q) * 64]);
      __syncthreads();  // staging complete
#pragma unroll
      for (int kk = 0; kk < 2; kk++) {
        const int oct = kk * 4 + q4;
        bf16x8 af[4];
#pragma unroll
        for (int i = 0; i < 4; i++) {
          const int ra = wm * 64 + i * 16 + m16;
          af[i] = *(const bf16x8*)&As[ra * 8 + (oct ^ xr)];
        }
#pragma unroll
        for (int j = 0; j < 8; j++) {
          const int rb = wn * 128 + j * 16 + m16;
          bf16x8 bf = *(const bf16x8*)&Bs[rb * 8 + (oct ^ xr)];
#pragma unroll
          for (int i = 0; i < 4; i++)
            acc[i][j] = __builtin_amdgcn_mfma_f32_16x16x32_bf16(af[i], bf, acc[i][j], 0, 0, 0);
        }
      }
    }

    // fold: argmin update + loss capture.  C/D: col=lane&15, row=(lane>>4)*4+reg
#pragma unroll
    for (int j = 0; j < 8; j++) {
      const int n = n0 + wn * 128 + j * 16 + m16;
      const float cc = c2s[n];
#pragma unroll
      for (int i = 0; i < 4; i++)
#pragma unroll
        for (int r = 0; r < 4; r++) {
          float v = fmaf(-2.f, acc[i][j][r], cc);
          const int bi = i * 4 + r;
          if (n == ysv[bi]) lsum += v;
          if (v < best[bi]) { best[bi] = v; bi_[bi] = n; }
        }
    }
  }

  // argmin cross-lane reduce + write
#pragma unroll
  for (int bi = 0; bi < 16; bi++) {
    float v = best[bi];
    int idx = bi_[bi];
#pragma unroll
    for (int off = 8; off; off >>= 1) {
      float ov = __shfl_xor(v, off, 64);
      int oi = __shfl_xor(idx, off, 64);
      if (ov < v || (ov == v && oi < idx)) { v = ov; idx = oi; }
    }
    if (m16 == 0) {
      const int m = wm * 64 + (bi >> 2) * 16 + q4 * 4 + (bi & 3);
      ynew_out[row0 + m] = (float)idx;
    }
  }

  // loss block reduce -> one partial per block
#pragma unroll
  for (int off = 32; off; off >>= 1) lsum += __shfl_down(lsum, off, 64);
  if (l == 0) lred[w] = lsum;
  __syncthreads();
  if (t == 0) ploss[blockIdx.x] = lred[0] + lred[1] + lred[2] + lred[3];
}

// out[0] = sum(px2[2048]) + sum(ploss[512])
__global__ __launch_bounds__(256) void loss_final(const float* __restrict__ px2,
                                                  const float* __restrict__ ploss,
                                                  float* __restrict__ out) {
  float s = 0.f;
#pragma unroll
  for (int j = 0; j < 8; j++) s += px2[threadIdx.x + 256 * j];
#pragma unroll
  for (int j = 0; j < 2; j++) s += ploss[threadIdx.x + 256 * j];
#pragma unroll
  for (int off = 32; off; off >>= 1) s += __shfl_down(s, off, 64);
  __shared__ float ps[4];
  if ((threadIdx.x & 63) == 0) ps[threadIdx.x >> 6] = s;
  __syncthreads();
  if (threadIdx.x == 0) out[0] = ps[0] + ps[1] + ps[2] + ps[3];
}

// ================= FALLBACK PATH (R2, used only if ws too small) =================

#define SLOT(row, oct) (16 * (oct) + (((row) & 15) ^ (((oct) & 2) << 1)))

__device__ __forceinline__ void split_pack(const float4& a, const float4& b,
                                           uint4& hi, uint4& lo) {
  float f[8] = {a.x, a.y, a.z, a.w, b.x, b.y, b.z, b.w};
  uint hw[4], lw[4];
#pragma unroll
  for (int i = 0; i < 4; i++) {
    uint e0 = __float_as_uint(f[2 * i]), e1 = __float_as_uint(f[2 * i + 1]);
    hw[i] = (e0 >> 16) | (e1 & 0xffff0000u);
    float l0 = f[2 * i]     - __uint_as_float(e0 & 0xffff0000u);
    float l1 = f[2 * i + 1] - __uint_as_float(e1 & 0xffff0000u);
    lw[i] = (__float_as_uint(l0) >> 16) | (__float_as_uint(l1) & 0xffff0000u);
  }
  hi = make_uint4(hw[0], hw[1], hw[2], hw[3]);
  lo = make_uint4(lw[0], lw[1], lw[2], lw[3]);
}

__global__ __launch_bounds__(256) void c2_kernel(const float* __restrict__ centers,
                                                 float* __restrict__ c2) {
  int wave = (blockIdx.x * 256 + threadIdx.x) >> 6;
  int lane = threadIdx.x & 63;
  const float4* c4 = (const float4*)(centers + (size_t)wave * DD);
  float s = 0.f;
#pragma unroll
  for (int j = 0; j < 2; j++) {
    float4 v = c4[lane + 64 * j];
    s += v.x * v.x + v.y * v.y + v.z * v.z + v.w * v.w;
  }
#pragma unroll
  for (int off = 32; off; off >>= 1) s += __shfl_down(s, off, 64);
  if (lane == 0) c2[wave] = s;
}

__global__ __launch_bounds__(256, 2) void argmin_fb(
    const float* __restrict__ x, const float* __restrict__ centers,
    const float* __restrict__ c2, float* __restrict__ ynew_out) {
  __shared__ uint4 Ah[512], Al[512], Bh[512], Bl[512];
  const int t = threadIdx.x;
  const int w = t >> 6, l = t & 63;
  const int wm = w >> 1, wn = w & 1;
  const size_t row0 = (size_t)blockIdx.x * 128;
  const int srow = t >> 1, h = t & 1;
  const int mt = srow >> 4;
  const int so0 = mt * 64 + SLOT(srow, 2 * h);
  const int so1 = mt * 64 + SLOT(srow, 2 * h + 1);
  const int rs = SLOT(l & 15, l >> 4);
  const float* xp = x + (row0 + srow) * DD + h * 16;
  float best[16];
  int bidx[16];
#pragma unroll
  for (int i = 0; i < 16; i++) { best[i] = 3.4e38f; bidx[i] = 0; }
  for (int n0 = 0; n0 < KC; n0 += 128) {
    const float* bp = centers + (size_t)(n0 + srow) * DD + h * 16;
    f32x4 acc[4][4];
#pragma unroll
    for (int i = 0; i < 4; i++)
#pragma unroll
      for (int j = 0; j < 4; j++) acc[i][j] = (f32x4){0.f, 0.f, 0.f, 0.f};
    float4 ra[4], rb[4];
#pragma unroll
    for (int q = 0; q < 4; q++) {
      ra[q] = *(const float4*)(xp + q * 4);
      rb[q] = *(const float4*)(bp + q * 4);
    }
    for (int ks = 0; ks < 16; ks++) {
      uint4 ah0, al0, ah1, al1, bh0, bl0, bh1, bl1;
      split_pack(ra[0], ra[1], ah0, al0);
      split_pack(ra[2], ra[3], ah1, al1);
      split_pack(rb[0], rb[1], bh0, bl0);
      split_pack(rb[2], rb[3], bh1, bl1);
      __syncthreads();
      Ah[so0] = ah0; Al[so0] = al0;
      Ah[so1] = ah1; Al[so1] = al1;
      Bh[so0] = bh0; Bl[so0] = bl0;
      Bh[so1] = bh1; Bl[so1] = bl1;
      __syncthreads();
      if (ks < 15) {
#pragma unroll
        for (int q = 0; q < 4; q++) {
          ra[q] = *(const float4*)(xp + (ks + 1) * 32 + q * 4);
          rb[q] = *(const float4*)(bp + (ks + 1) * 32 + q * 4);
        }
      }
      bf16x8 afh[4], afl[4], bfh[4], bfl[4];
#pragma unroll
      for (int i = 0; i < 4; i++) {
        afh[i] = *(const bf16x8*)&Ah[(wm * 4 + i) * 64 + rs];
        afl[i] = *(const bf16x8*)&Al[(wm * 4 + i) * 64 + rs];
        bfh[i] = *(const bf16x8*)&Bh[(wn * 4 + i) * 64 + rs];
        bfl[i] = *(const bf16x8*)&Bl[(wn * 4 + i) * 64 + rs];
      }
#pragma unroll
      for (int i = 0; i < 4; i++)
#pragma unroll
        for (int j = 0; j < 4; j++) {
          acc[i][j] = __builtin_amdgcn_mfma_f32_16x16x32_bf16(afh[i], bfh[j], acc[i][j], 0, 0, 0);
          acc[i][j] = __builtin_amdgcn_mfma_f32_16x16x32_bf16(afl[i], bfh[j], acc[i][j], 0, 0, 0);
          acc[i][j] = __builtin_amdgcn_mfma_f32_16x16x32_bf16(afh[i], bfl[j], acc[i][j], 0, 0, 0);
        }
    }
#pragma unroll
    for (int j = 0; j < 4; j++) {
      int n = n0 + wn * 64 + j * 16 + (l & 15);
      float cc = c2[n];
#pragma unroll
      for (int i = 0; i < 4; i++)
#pragma unroll
        for (int r = 0; r < 4; r++) {
          float v = fmaf(-2.f, acc[i][j][r], cc);
          int bi = i * 4 + r;
          if (v < best[bi]) { best[bi] = v; bidx[bi] = n; }
        }
    }
  }
#pragma unroll
  for (int bi = 0; bi < 16; bi++) {
    float v = best[bi];
    int idx = bidx[bi];
#pragma unroll
    for (int off = 8; off; off >>= 1) {
      float ov = __shfl_xor(v, off, 64);
      int oi = __shfl_xor(idx, off, 64);
      if (ov < v || (ov == v && oi < idx)) { v = ov; idx = oi; }
    }
    if ((l & 15) == 0) {
      int m = wm * 64 + (bi >> 2) * 16 + (l >> 4) * 4 + (bi & 3);
      ynew_out[row0 + m] = (float)idx;
    }
  }
}

__global__ __launch_bounds__(256) void loss_partial_fb(
    const float* __restrict__ x, const int* __restrict__ y,
    const float* __restrict__ centers, float* __restrict__ partial) {
  const int w = threadIdx.x >> 6, l = threadIdx.x & 63;
  const int row = blockIdx.x * 4 + w;
  const float4* x4 = (const float4*)(x + (size_t)row * DD);
  const float4* c4 = (const float4*)(centers + (size_t)y[row] * DD);
  float s = 0.f;
#pragma unroll
  for (int j = 0; j < 2; j++) {
    float4 xv = x4[2 * l + j], cv = c4[2 * l + j];
    float dx = xv.x - cv.x, dy = xv.y - cv.y, dz = xv.z - cv.z, dw = xv.w - cv.w;
    s += dx * dx + dy * dy + dz * dz + dw * dw;
  }
#pragma unroll
  for (int off = 32; off; off >>= 1) s += __shfl_down(s, off, 64);
  __shared__ float ps[4];
  if (l == 0) ps[w] = s;
  __syncthreads();
  if (threadIdx.x == 0) partial[blockIdx.x] = ps[0] + ps[1] + ps[2] + ps[3];
}

__global__ __launch_bounds__(256) void loss_final_fb(const float* __restrict__ partial,
                                                     float* __restrict__ out) {
  float s = 0.f;
#pragma unroll
  for (int j = 0; j < 64; j++) s += partial[threadIdx.x + 256 * j];
#pragma unroll
  for (int off = 32; off; off >>= 1) s += __shfl_down(s, off, 64);
  __shared__ float ps[4];
  if ((threadIdx.x & 63) == 0) ps[threadIdx.x >> 6] = s;
  __syncthreads();
  if (threadIdx.x == 0) out[0] = ps[0] + ps[1] + ps[2] + ps[3];
}

// ================= launcher =================

extern "C" void kernel_launch(void* const* d_in, const int* in_sizes, int n_in,
                              void* d_out, int out_size, void* d_ws, size_t ws_size,
                              hipStream_t stream) {
  const float* x       = (const float*)d_in[0];
  const int*   y       = (const int*)d_in[1];
  const float* centers = (const float*)d_in[2];
  float* out = (float*)d_out;  // out[0] = loss, out[1..] = ynew as float

  const size_t xb_bytes = (size_t)NPTS * DD * 2;  // 64 MB
  const size_t cb_bytes = (size_t)KC * DD * 2;    // 1 MB
  const size_t need = xb_bytes + cb_bytes + (KC + 2048 + 512) * sizeof(float);

  if (ws_size >= need) {
    uint4* xb    = (uint4*)d_ws;
    uint4* cbp   = (uint4*)((char*)d_ws + xb_bytes);
    float* c2    = (float*)((char*)d_ws + xb_bytes + cb_bytes);
    float* px2   = c2 + KC;          // 2048
    float* ploss = px2 + 2048;       // 512
    prep_kernel<<<256 + 2048, 256, 0, stream>>>(x, centers, xb, cbp, c2, px2);
    gemm_argmin<<<NPTS / 128, 256, 0, stream>>>(xb, cbp, c2, y, out + 1, ploss);
    loss_final<<<1, 256, 0, stream>>>(px2, ploss, out);
  } else {
    float* c2      = (float*)d_ws;
    float* partial = c2 + KC;
    c2_kernel<<<KC / 4, 256, 0, stream>>>(centers, c2);
    argmin_fb<<<NPTS / 128, 256, 0, stream>>>(x, centers, c2, out + 1);
    loss_partial_fb<<<NPTS / 4, 256, 0, stream>>>(x, y, centers, partial);
    loss_final_fb<<<1, 256, 0, stream>>>(partial, out);
  }
}

// Round 6
// 281.697 us; speedup vs baseline: 1.1153x; 1.1153x over previous
//
#include <hip/hip_runtime.h>

#define NPTS 65536
#define KC   1024
#define DD   512

using bf16x8 = __attribute__((ext_vector_type(8))) __bf16;
using f32x4  = __attribute__((ext_vector_type(4))) float;

// ---- async global->LDS, 16B per lane. LDS dest = wave-uniform base + lane*16.
__device__ __forceinline__ void gld_lds16(const void* g, void* lds_base) {
  __builtin_amdgcn_global_load_lds(
      (const __attribute__((address_space(1))) unsigned int*)(uintptr_t)g,
      (__attribute__((address_space(3))) unsigned int*)(unsigned int)(uintptr_t)lds_base,
      16, 0, 0);
}

// pack float4 -> 4 bf16 (truncation)
__device__ __forceinline__ uint2 pack4(const float4& v) {
  uint2 r;
  r.x = (__float_as_uint(v.x) >> 16) | (__float_as_uint(v.y) & 0xffff0000u);
  r.y = (__float_as_uint(v.z) >> 16) | (__float_as_uint(v.w) & 0xffff0000u);
  return r;
}

// ================= FAST PATH =================

// fused prep: blocks [0,256) convert centers->cb + c2 (1024 rows);
// blocks [256, 256+2048) convert x->xb (8 rows/wave) + x2 block partials.
// Pure streaming: no gathers, no long dependence chains.
__global__ __launch_bounds__(256) void prep_kernel(
    const float* __restrict__ x, const float* __restrict__ centers,
    uint4* __restrict__ xb, uint4* __restrict__ cb,
    float* __restrict__ c2, float* __restrict__ px2) {
  const int w = threadIdx.x >> 6, l = threadIdx.x & 63;
  if (blockIdx.x < 256) {
    const int row = blockIdx.x * 4 + w;
    const float4* cf4 = (const float4*)centers;
    float4 a = cf4[row * 128 + 2 * l];
    float4 b = cf4[row * 128 + 2 * l + 1];
    uint2 pa = pack4(a), pb = pack4(b);
    cb[row * 64 + l] = make_uint4(pa.x, pa.y, pb.x, pb.y);
    float s = a.x * a.x + a.y * a.y + a.z * a.z + a.w * a.w +
              b.x * b.x + b.y * b.y + b.z * b.z + b.w * b.w;
#pragma unroll
    for (int off = 32; off; off >>= 1) s += __shfl_down(s, off, 64);
    if (l == 0) c2[row] = s;
    return;
  }
  const int xblk = blockIdx.x - 256;         // 0..2047
  const int base = xblk * 32 + w * 8;        // 8 rows per wave
  const float4* xf4 = (const float4*)x;
  float s = 0.f;
#pragma unroll
  for (int p = 0; p < 8; p++) {
    const int row = base + p;
    float4 a = xf4[row * 128 + 2 * l];
    float4 b = xf4[row * 128 + 2 * l + 1];
    uint2 pa = pack4(a), pb = pack4(b);
    xb[row * 64 + l] = make_uint4(pa.x, pa.y, pb.x, pb.y);
    s += a.x * a.x + a.y * a.y + a.z * a.z + a.w * a.w +
         b.x * b.x + b.y * b.y + b.z * b.z + b.w * b.w;
  }
#pragma unroll
  for (int off = 32; off; off >>= 1) s += __shfl_down(s, off, 64);
  __shared__ float ps[4];
  if (l == 0) ps[w] = s;
  __syncthreads();
  if (threadIdx.x == 0) px2[xblk] = ps[0] + ps[1] + ps[2] + ps[3];
}

// bf16 MFMA argmin + loss capture.  BM=128 x BN=256, BK=64.
// __launch_bounds__(256,2): unified VGPR+AGPR pool is 512/SIMD (m69), this
// kernel needs ~236 regs/wave (128 AGPR acc + ~108 VGPR) -> 2 waves/SIMD max.
// (256,3) in R5 forced a 170-reg cap -> 85 MB of accumulator spill. Never again.
__global__ __launch_bounds__(256, 2) void gemm_argmin(
    const uint4* __restrict__ xb, const uint4* __restrict__ cb,
    const float* __restrict__ c2, const int* __restrict__ y,
    float* __restrict__ ynew_out, float* __restrict__ ploss) {
  __shared__ uint4 As[1024];   // 128 rows x 8 slots (64 bf16/row chunk)
  __shared__ uint4 Bs[2048];   // 256 rows x 8 slots
  __shared__ float c2s[1024];
  __shared__ int   ys[128];
  __shared__ float lred[4];

  const int t = threadIdx.x;
  const int w = t >> 6, l = t & 63;
  const int wm = w >> 1, wn = w & 1;   // wave: 64 rows x 128 cols
  const int q4 = l >> 4, m16 = l & 15;
  const int row0 = blockIdx.x * 128;

#pragma unroll
  for (int i = 0; i < 4; i++) c2s[t + 256 * i] = c2[t + 256 * i];
  if (t < 128) ys[t] = y[row0 + t];
  __syncthreads();

  // per-lane copy of y for the 16 accumulator rows this lane owns
  int ysv[16];
#pragma unroll
  for (int i = 0; i < 4; i++)
#pragma unroll
    for (int r = 0; r < 4; r++)
      ysv[i * 4 + r] = ys[wm * 64 + i * 16 + q4 * 4 + r];

  // staging lane mapping: chunk covers 8 rows; lane l -> row l>>3, slot l&7,
  // source oct (l&7)^(l>>3)  => LDS slot(r,oct) = oct ^ (r&7)  (conflict-free)
  const int r_l = l >> 3;
  const int o_l = (l & 7) ^ r_l;
  int aidx[4];
#pragma unroll
  for (int q = 0; q < 4; q++)
    aidx[q] = (row0 + (w * 4 + q) * 8 + r_l) * 64 + o_l;
  int bsrc[8];
#pragma unroll
  for (int q = 0; q < 8; q++)
    bsrc[q] = ((w * 8 + q) * 8 + r_l) * 64 + o_l;

  const int xr = m16 & 7;

  float best[16];
  int bi_[16];
#pragma unroll
  for (int i = 0; i < 16; i++) { best[i] = 3.4e38f; bi_[i] = 0; }
  float lsum = 0.f;

  for (int n0 = 0; n0 < KC; n0 += 256) {
    f32x4 acc[4][8];
#pragma unroll
    for (int i = 0; i < 4; i++)
#pragma unroll
      for (int j = 0; j < 8; j++) acc[i][j] = (f32x4){0.f, 0.f, 0.f, 0.f};

    const uint4* bbase = cb + n0 * 64;

    for (int ks = 0; ks < 8; ks++) {
      __syncthreads();  // previous iteration's fragment reads complete
#pragma unroll
      for (int q = 0; q < 4; q++)
        gld_lds16(xb + aidx[q] + ks * 8, &As[(w * 4 + q) * 64]);
#pragma unroll
      for (int q = 0; q < 8; q++)
        gld_lds16(bbase + bsrc[q] + ks * 8, &Bs[(w * 8 + q) * 64]);
      __syncthreads();  // staging complete
#pragma unroll
      for (int kk = 0; kk < 2; kk++) {
        const int oct = kk * 4 + q4;
        bf16x8 af[4];
#pragma unroll
        for (int i = 0; i < 4; i++) {
          const int ra = wm * 64 + i * 16 + m16;
          af[i] = *(const bf16x8*)&As[ra * 8 + (oct ^ xr)];
        }
#pragma unroll
        for (int j = 0; j < 8; j++) {
          const int rb = wn * 128 + j * 16 + m16;
          bf16x8 bf = *(const bf16x8*)&Bs[rb * 8 + (oct ^ xr)];
#pragma unroll
          for (int i = 0; i < 4; i++)
            acc[i][j] = __builtin_amdgcn_mfma_f32_16x16x32_bf16(af[i], bf, acc[i][j], 0, 0, 0);
        }
      }
    }

    // fold: argmin update + loss capture.  C/D: col=lane&15, row=(lane>>4)*4+reg
#pragma unroll
    for (int j = 0; j < 8; j++) {
      const int n = n0 + wn * 128 + j * 16 + m16;
      const float cc = c2s[n];
#pragma unroll
      for (int i = 0; i < 4; i++)
#pragma unroll
        for (int r = 0; r < 4; r++) {
          float v = fmaf(-2.f, acc[i][j][r], cc);
          const int bi = i * 4 + r;
          if (n == ysv[bi]) lsum += v;
          if (v < best[bi]) { best[bi] = v; bi_[bi] = n; }
        }
    }
  }

  // argmin cross-lane reduce + write
#pragma unroll
  for (int bi = 0; bi < 16; bi++) {
    float v = best[bi];
    int idx = bi_[bi];
#pragma unroll
    for (int off = 8; off; off >>= 1) {
      float ov = __shfl_xor(v, off, 64);
      int oi = __shfl_xor(idx, off, 64);
      if (ov < v || (ov == v && oi < idx)) { v = ov; idx = oi; }
    }
    if (m16 == 0) {
      const int m = wm * 64 + (bi >> 2) * 16 + q4 * 4 + (bi & 3);
      ynew_out[row0 + m] = (float)idx;
    }
  }

  // loss block reduce -> one partial per block
#pragma unroll
  for (int off = 32; off; off >>= 1) lsum += __shfl_down(lsum, off, 64);
  if (l == 0) lred[w] = lsum;
  __syncthreads();
  if (t == 0) ploss[blockIdx.x] = lred[0] + lred[1] + lred[2] + lred[3];
}

// out[0] = sum(px2[2048]) + sum(ploss[512])
__global__ __launch_bounds__(256) void loss_final(const float* __restrict__ px2,
                                                  const float* __restrict__ ploss,
                                                  float* __restrict__ out) {
  float s = 0.f;
#pragma unroll
  for (int j = 0; j < 8; j++) s += px2[threadIdx.x + 256 * j];
#pragma unroll
  for (int j = 0; j < 2; j++) s += ploss[threadIdx.x + 256 * j];
#pragma unroll
  for (int off = 32; off; off >>= 1) s += __shfl_down(s, off, 64);
  __shared__ float ps[4];
  if ((threadIdx.x & 63) == 0) ps[threadIdx.x >> 6] = s;
  __syncthreads();
  if (threadIdx.x == 0) out[0] = ps[0] + ps[1] + ps[2] + ps[3];
}

// ================= FALLBACK PATH (R2, used only if ws too small) =================

#define SLOT(row, oct) (16 * (oct) + (((row) & 15) ^ (((oct) & 2) << 1)))

__device__ __forceinline__ void split_pack(const float4& a, const float4& b,
                                           uint4& hi, uint4& lo) {
  float f[8] = {a.x, a.y, a.z, a.w, b.x, b.y, b.z, b.w};
  uint hw[4], lw[4];
#pragma unroll
  for (int i = 0; i < 4; i++) {
    uint e0 = __float_as_uint(f[2 * i]), e1 = __float_as_uint(f[2 * i + 1]);
    hw[i] = (e0 >> 16) | (e1 & 0xffff0000u);
    float l0 = f[2 * i]     - __uint_as_float(e0 & 0xffff0000u);
    float l1 = f[2 * i + 1] - __uint_as_float(e1 & 0xffff0000u);
    lw[i] = (__float_as_uint(l0) >> 16) | (__float_as_uint(l1) & 0xffff0000u);
  }
  hi = make_uint4(hw[0], hw[1], hw[2], hw[3]);
  lo = make_uint4(lw[0], lw[1], lw[2], lw[3]);
}

__global__ __launch_bounds__(256) void c2_kernel(const float* __restrict__ centers,
                                                 float* __restrict__ c2) {
  int wave = (blockIdx.x * 256 + threadIdx.x) >> 6;
  int lane = threadIdx.x & 63;
  const float4* c4 = (const float4*)(centers + (size_t)wave * DD);
  float s = 0.f;
#pragma unroll
  for (int j = 0; j < 2; j++) {
    float4 v = c4[lane + 64 * j];
    s += v.x * v.x + v.y * v.y + v.z * v.z + v.w * v.w;
  }
#pragma unroll
  for (int off = 32; off; off >>= 1) s += __shfl_down(s, off, 64);
  if (lane == 0) c2[wave] = s;
}

__global__ __launch_bounds__(256, 2) void argmin_fb(
    const float* __restrict__ x, const float* __restrict__ centers,
    const float* __restrict__ c2, float* __restrict__ ynew_out) {
  __shared__ uint4 Ah[512], Al[512], Bh[512], Bl[512];
  const int t = threadIdx.x;
  const int w = t >> 6, l = t & 63;
  const int wm = w >> 1, wn = w & 1;
  const size_t row0 = (size_t)blockIdx.x * 128;
  const int srow = t >> 1, h = t & 1;
  const int mt = srow >> 4;
  const int so0 = mt * 64 + SLOT(srow, 2 * h);
  const int so1 = mt * 64 + SLOT(srow, 2 * h + 1);
  const int rs = SLOT(l & 15, l >> 4);
  const float* xp = x + (row0 + srow) * DD + h * 16;
  float best[16];
  int bidx[16];
#pragma unroll
  for (int i = 0; i < 16; i++) { best[i] = 3.4e38f; bidx[i] = 0; }
  for (int n0 = 0; n0 < KC; n0 += 128) {
    const float* bp = centers + (size_t)(n0 + srow) * DD + h * 16;
    f32x4 acc[4][4];
#pragma unroll
    for (int i = 0; i < 4; i++)
#pragma unroll
      for (int j = 0; j < 4; j++) acc[i][j] = (f32x4){0.f, 0.f, 0.f, 0.f};
    float4 ra[4], rb[4];
#pragma unroll
    for (int q = 0; q < 4; q++) {
      ra[q] = *(const float4*)(xp + q * 4);
      rb[q] = *(const float4*)(bp + q * 4);
    }
    for (int ks = 0; ks < 16; ks++) {
      uint4 ah0, al0, ah1, al1, bh0, bl0, bh1, bl1;
      split_pack(ra[0], ra[1], ah0, al0);
      split_pack(ra[2], ra[3], ah1, al1);
      split_pack(rb[0], rb[1], bh0, bl0);
      split_pack(rb[2], rb[3], bh1, bl1);
      __syncthreads();
      Ah[so0] = ah0; Al[so0] = al0;
      Ah[so1] = ah1; Al[so1] = al1;
      Bh[so0] = bh0; Bl[so0] = bl0;
      Bh[so1] = bh1; Bl[so1] = bl1;
      __syncthreads();
      if (ks < 15) {
#pragma unroll
        for (int q = 0; q < 4; q++) {
          ra[q] = *(const float4*)(xp + (ks + 1) * 32 + q * 4);
          rb[q] = *(const float4*)(bp + (ks + 1) * 32 + q * 4);
        }
      }
      bf16x8 afh[4], afl[4], bfh[4], bfl[4];
#pragma unroll
      for (int i = 0; i < 4; i++) {
        afh[i] = *(const bf16x8*)&Ah[(wm * 4 + i) * 64 + rs];
        afl[i] = *(const bf16x8*)&Al[(wm * 4 + i) * 64 + rs];
        bfh[i] = *(const bf16x8*)&Bh[(wn * 4 + i) * 64 + rs];
        bfl[i] = *(const bf16x8*)&Bl[(wn * 4 + i) * 64 + rs];
      }
#pragma unroll
      for (int i = 0; i < 4; i++)
#pragma unroll
        for (int j = 0; j < 4; j++) {
          acc[i][j] = __builtin_amdgcn_mfma_f32_16x16x32_bf16(afh[i], bfh[j], acc[i][j], 0, 0, 0);
          acc[i][j] = __builtin_amdgcn_mfma_f32_16x16x32_bf16(afl[i], bfh[j], acc[i][j], 0, 0, 0);
          acc[i][j] = __builtin_amdgcn_mfma_f32_16x16x32_bf16(afh[i], bfl[j], acc[i][j], 0, 0, 0);
        }
    }
#pragma unroll
    for (int j = 0; j < 4; j++) {
      int n = n0 + wn * 64 + j * 16 + (l & 15);
      float cc = c2[n];
#pragma unroll
      for (int i = 0; i < 4; i++)
#pragma unroll
        for (int r = 0; r < 4; r++) {
          float v = fmaf(-2.f, acc[i][j][r], cc);
          int bi = i * 4 + r;
          if (v < best[bi]) { best[bi] = v; bidx[bi] = n; }
        }
    }
  }
#pragma unroll
  for (int bi = 0; bi < 16; bi++) {
    float v = best[bi];
    int idx = bidx[bi];
#pragma unroll
    for (int off = 8; off; off >>= 1) {
      float ov = __shfl_xor(v, off, 64);
      int oi = __shfl_xor(idx, off, 64);
      if (ov < v || (ov == v && oi < idx)) { v = ov; idx = oi; }
    }
    if ((l & 15) == 0) {
      int m = wm * 64 + (bi >> 2) * 16 + (l >> 4) * 4 + (bi & 3);
      ynew_out[row0 + m] = (float)idx;
    }
  }
}

__global__ __launch_bounds__(256) void loss_partial_fb(
    const float* __restrict__ x, const int* __restrict__ y,
    const float* __restrict__ centers, float* __restrict__ partial) {
  const int w = threadIdx.x >> 6, l = threadIdx.x & 63;
  const int row = blockIdx.x * 4 + w;
  const float4* x4 = (const float4*)(x + (size_t)row * DD);
  const float4* c4 = (const float4*)(centers + (size_t)y[row] * DD);
  float s = 0.f;
#pragma unroll
  for (int j = 0; j < 2; j++) {
    float4 xv = x4[2 * l + j], cv = c4[2 * l + j];
    float dx = xv.x - cv.x, dy = xv.y - cv.y, dz = xv.z - cv.z, dw = xv.w - cv.w;
    s += dx * dx + dy * dy + dz * dz + dw * dw;
  }
#pragma unroll
  for (int off = 32; off; off >>= 1) s += __shfl_down(s, off, 64);
  __shared__ float ps[4];
  if (l == 0) ps[w] = s;
  __syncthreads();
  if (threadIdx.x == 0) partial[blockIdx.x] = ps[0] + ps[1] + ps[2] + ps[3];
}

__global__ __launch_bounds__(256) void loss_final_fb(const float* __restrict__ partial,
                                                     float* __restrict__ out) {
  float s = 0.f;
#pragma unroll
  for (int j = 0; j < 64; j++) s += partial[threadIdx.x + 256 * j];
#pragma unroll
  for (int off = 32; off; off >>= 1) s += __shfl_down(s, off, 64);
  __shared__ float ps[4];
  if ((threadIdx.x & 63) == 0) ps[threadIdx.x >> 6] = s;
  __syncthreads();
  if (threadIdx.x == 0) out[0] = ps[0] + ps[1] + ps[2] + ps[3];
}

// ================= launcher =================

extern "C" void kernel_launch(void* const* d_in, const int* in_sizes, int n_in,
                              void* d_out, int out_size, void* d_ws, size_t ws_size,
                              hipStream_t stream) {
  const float* x       = (const float*)d_in[0];
  const int*   y       = (const int*)d_in[1];
  const float* centers = (const float*)d_in[2];
  float* out = (float*)d_out;  // out[0] = loss, out[1..] = ynew as float

  const size_t xb_bytes = (size_t)NPTS * DD * 2;  // 64 MB
  const size_t cb_bytes = (size_t)KC * DD * 2;    // 1 MB
  const size_t need = xb_bytes + cb_bytes + (KC + 2048 + 512) * sizeof(float);

  if (ws_size >= need) {
    uint4* xb    = (uint4*)d_ws;
    uint4* cbp   = (uint4*)((char*)d_ws + xb_bytes);
    float* c2    = (float*)((char*)d_ws + xb_bytes + cb_bytes);
    float* px2   = c2 + KC;          // 2048
    float* ploss = px2 + 2048;       // 512
    prep_kernel<<<256 + 2048, 256, 0, stream>>>(x, centers, xb, cbp, c2, px2);
    gemm_argmin<<<NPTS / 128, 256, 0, stream>>>(xb, cbp, c2, y, out + 1, ploss);
    loss_final<<<1, 256, 0, stream>>>(px2, ploss, out);
  } else {
    float* c2      = (float*)d_ws;
    float* partial = c2 + KC;
    c2_kernel<<<KC / 4, 256, 0, stream>>>(centers, c2);
    argmin_fb<<<NPTS / 128, 256, 0, stream>>>(x, centers, c2, out + 1);
    loss_partial_fb<<<NPTS / 4, 256, 0, stream>>>(x, y, centers, partial);
    loss_final_fb<<<1, 256, 0, stream>>>(partial, out);
  }
}